// Round 8
// baseline (138.566 us; speedup 1.0000x reference)
//
#include <hip/hip_runtime.h>
#include <hip/hip_bf16.h>
#include <stdint.h>

typedef unsigned short u16;
typedef unsigned int u32;
typedef unsigned long long u64;
typedef __attribute__((ext_vector_type(8))) short short8;
typedef __attribute__((ext_vector_type(4))) float f32x4;

#define LOG2E 1.44269504f

static __device__ __forceinline__ u16 f2bf(float f) {
    u32 x = __float_as_uint(f);
    u32 r = (x + 0x7FFFu + ((x >> 16) & 1u)) >> 16;
    return (u16)r;
}
static __device__ __forceinline__ float bf2f(u16 u) {
    return __uint_as_float(((u32)u) << 16);
}
static __device__ __forceinline__ u32 pk2(float lo, float hi) {
    __hip_bfloat162 t = __float22bfloat162_rn(float2{lo, hi});
    union { __hip_bfloat162 b; u32 u; } cv;
    cv.b = t;
    return cv.u;
}
static __device__ __forceinline__ float fexp2(float x) {
#if __has_builtin(__builtin_amdgcn_exp2f)
    return __builtin_amdgcn_exp2f(x);
#else
    return exp2f(x);
#endif
}

static __device__ __forceinline__ void g2l16(const void* g, void* l) {
    __builtin_amdgcn_global_load_lds((const __attribute__((address_space(1))) void*)g,
                                     (__attribute__((address_space(3))) void*)l, 16, 0, 0);
}

// ---------------------------------------------------------------- convert (all tensors, one launch)
__global__ __launch_bounds__(256) void k_cvt_all(
    const float* __restrict__ q_in, const float* __restrict__ kv_in,
    const float* __restrict__ Wq, const float* __restrict__ Wk,
    const float* __restrict__ Wv, const float* __restrict__ Wp,
    const float* __restrict__ Wdy2, const float* __restrict__ Wdy,
    u16* __restrict__ qbf, u16* __restrict__ kvbf, u16* __restrict__ Wqb,
    u16* __restrict__ Wkb, u16* __restrict__ Wvb, u16* __restrict__ Wpb,
    u16* __restrict__ wgb) {
    int i = blockIdx.x * 256 + threadIdx.x;
    const float* src;
    u16* dst;
    int so, dofs;
    if (i < 786432) { src = q_in; dst = qbf; so = i; dofs = i; }
    else if (i < 1572864) { src = kv_in; dst = kvbf; so = i - 786432; dofs = so; }
    else if (i < 1646592) { src = Wq; dst = Wqb; so = i - 1572864; dofs = so; }
    else if (i < 1720320) { src = Wk; dst = Wkb; so = i - 1646592; dofs = so; }
    else if (i < 1794048) { src = Wv; dst = Wvb; so = i - 1720320; dofs = so; }
    else if (i < 1867776) { src = Wp; dst = Wpb; so = i - 1794048; dofs = so; }
    else if (i < 1870080) {
        int e = i - 1867776;
        dst = wgb; dofs = e;
        if (e < 1152) { src = Wdy2; so = e; }
        else { src = Wdy; so = e - 1152; }
    } else return;
    const float4* p = (const float4*)src + (size_t)so * 2;
    float4 a = p[0], b = p[1];
    short8 o;
    o[0] = f2bf(a.x); o[1] = f2bf(a.y); o[2] = f2bf(a.z); o[3] = f2bf(a.w);
    o[4] = f2bf(b.x); o[5] = f2bf(b.y); o[6] = f2bf(b.z); o[7] = f2bf(b.w);
    *((short8*)dst + dofs) = o;
}

// ---------------------------------------------------------------- gates (1-wave blocks)
__global__ __launch_bounds__(64) void k_gates(
    const u16* __restrict__ qbf, const u16* __restrict__ wgb,
    const float* __restrict__ bdy2, const float* __restrict__ bdy,
    const float* __restrict__ star_s, const float* __restrict__ star_b,
    float* __restrict__ glf, float* __restrict__ ghf) {
    int lane = threadIdx.x;
    int g = lane >> 4, c = lane & 15;
    int row0 = blockIdx.x * 16;
    float ss = star_s[0], sb = star_b[0];
    f32x4 acc[2];
    acc[0] = (f32x4){0.f, 0.f, 0.f, 0.f};
    acc[1] = (f32x4){0.f, 0.f, 0.f, 0.f};
    for (int t = 0; t < 24; ++t) {
        int k0 = t * 32;
        short8 x8 = *(const short8*)(qbf + (size_t)(row0 + c) * 768 + k0 + g * 8);
        float f[8];
#pragma unroll
        for (int j = 0; j < 8; ++j) {
            float x = fmaxf(bf2f((u16)x8[j]), 0.f);
            f[j] = ss * x * x + sb;
        }
        union { u32 u[4]; short8 s8; } au;
#pragma unroll
        for (int j = 0; j < 4; ++j) au.u[j] = pk2(f[2 * j], f[2 * j + 1]);
        short8 b0 = *(const short8*)(wgb + (size_t)c * 768 + k0 + g * 8);
        short8 b1 = (short8){0, 0, 0, 0, 0, 0, 0, 0};
        if (c < 8)
            b1 = *(const short8*)(wgb + (size_t)(16 + c) * 768 + k0 + g * 8);
        acc[0] = __builtin_amdgcn_mfma_f32_16x16x32_bf16(au.s8, b0, acc[0], 0, 0, 0);
        acc[1] = __builtin_amdgcn_mfma_f32_16x16x32_bf16(au.s8, b1, acc[1], 0, 0, 0);
    }
#pragma unroll
    for (int n = 0; n < 2; ++n)
#pragma unroll
        for (int r = 0; r < 4; ++r) {
            int token = row0 + g * 4 + r;
            int o = n * 16 + c;
            float v = acc[n][r];
            if (o < 12) {
                glf[(size_t)token * 12 + o] = tanhf(v + bdy2[o]);
            } else if (o < 24) {
                float x = v + bdy[o - 12];
                float sp = (x > 15.f) ? x : log1pf(expf(x));
                float d2 = sp * sp;
                ghf[(size_t)token * 12 + (o - 12)] = 2.f * d2 / (d2 + 0.3678f);
            }
        }
}

// ---------------------------------------------------------------- fused Q|KV GEMM
// One kernel, 768 blocks: 384 Q-tiles (1 B matrix) + 384 KV-tiles (2 B
// matrices sharing one A staging).  2-buffer, 2-barrier, counted vmcnt.
// Pair-line swizzled LDS (zero-conflict), inverse swizzle on global source.
template <int NB>
__device__ __forceinline__ void gemm_nb(const u16* __restrict__ A,
                                        const u16* __restrict__ W0,
                                        const u16* __restrict__ W1, u16* smem,
                                        int rowA0, int rowB0, int lane, int w,
                                        int wm, int wn, f32x4 acc0[4][4],
                                        f32x4 acc1[4][4]) {
    int g = lane >> 4, c = lane & 15;
    u16* As = smem;
    u16* B0 = smem + 8192;
    u16* B1 = smem + 16384;

    auto stage = [&](int buf, int k0) {
#pragma unroll
        for (int j = 0; j < 2; ++j) {
            int L = w * 128 + j * 64 + lane;  // 16B unit 0..511
            int p = L >> 3, s8 = L & 7;
            int t2 = s8 ^ (p & 7);
            int row = 2 * p + (t2 >> 2);
            int chunk = t2 & 3;
            size_t go = (size_t)row * 768 + k0 + chunk * 8;
            g2l16(A + (size_t)rowA0 * 768 + go, As + buf * 4096 + L * 8);
            g2l16(W0 + (size_t)rowB0 * 768 + go, B0 + buf * 4096 + L * 8);
            if (NB == 2)
                g2l16(W1 + (size_t)rowB0 * 768 + go, B1 + buf * 4096 + L * 8);
        }
    };

    stage(0, 0);
    int buf = 0;
    for (int t = 0; t < 24; ++t) {
        if (t < 23) stage(buf ^ 1, (t + 1) * 32);
        // my tile-t loads landed (the 2*(1+NB) newest outstanding are t+1's)
        if (t < 23) {
            if (NB == 2) asm volatile("s_waitcnt vmcnt(6)" ::: "memory");
            else         asm volatile("s_waitcnt vmcnt(4)" ::: "memory");
        } else {
            asm volatile("s_waitcnt vmcnt(0)" ::: "memory");
        }
        __builtin_amdgcn_s_barrier();  // all waves: tile t in LDS
        short8 a[4], b0[4], b1[4];
#pragma unroll
        for (int m = 0; m < 4; ++m) {
            int row = wm * 64 + m * 16 + c;
            int off = (row >> 1) * 64 +
                      ((((row & 1) << 2) | g) ^ ((row >> 1) & 7)) * 8;
            a[m] = *(const short8*)(As + buf * 4096 + off);
        }
#pragma unroll
        for (int n = 0; n < 4; ++n) {
            int row = wn * 64 + n * 16 + c;
            int off = (row >> 1) * 64 +
                      ((((row & 1) << 2) | g) ^ ((row >> 1) & 7)) * 8;
            b0[n] = *(const short8*)(B0 + buf * 4096 + off);
            if (NB == 2) b1[n] = *(const short8*)(B1 + buf * 4096 + off);
        }
        __builtin_amdgcn_s_setprio(1);
#pragma unroll
        for (int m = 0; m < 4; ++m)
#pragma unroll
            for (int n = 0; n < 4; ++n)
                acc0[m][n] = __builtin_amdgcn_mfma_f32_16x16x32_bf16(
                    a[m], b0[n], acc0[m][n], 0, 0, 0);
        if (NB == 2) {
#pragma unroll
            for (int m = 0; m < 4; ++m)
#pragma unroll
                for (int n = 0; n < 4; ++n)
                    acc1[m][n] = __builtin_amdgcn_mfma_f32_16x16x32_bf16(
                        a[m], b1[n], acc1[m][n], 0, 0, 0);
        }
        __builtin_amdgcn_s_setprio(0);
        __builtin_amdgcn_s_barrier();  // all reads of buf done before restage
        buf ^= 1;
    }
}

__global__ __launch_bounds__(256, 2) void k_gemm_qkv(
    const u16* __restrict__ qbf, const u16* __restrict__ kvbf,
    const u16* __restrict__ Wqb, const u16* __restrict__ Wkb,
    const u16* __restrict__ Wvb, u16* __restrict__ Qb, u16* __restrict__ Kb,
    u16* __restrict__ VTg, u16* __restrict__ vlin) {
    __shared__ __align__(16) u16 smem[24576];  // 48 KB
    int bid = blockIdx.x;
    // XCD-chunked: 96 logical per XCD = 8 panels x (6 Q + 6 KV)
    int logical = (bid & 7) * 96 + (bid >> 3);
    int panel = logical / 12, sub = logical % 12;
    bool isQ = (sub < 6);
    int tn = sub % 6;
    int tid = threadIdx.x, lane = tid & 63, w = tid >> 6;
    int g = lane >> 4, c = lane & 15;
    int wm = w >> 1, wn = w & 1;
    int rowA0 = panel * 128, rowB0 = tn * 128;

    f32x4 acc0[4][4], acc1[4][4];
#pragma unroll
    for (int m = 0; m < 4; ++m)
#pragma unroll
        for (int n = 0; n < 4; ++n) {
            acc0[m][n] = (f32x4){0.f, 0.f, 0.f, 0.f};
            acc1[m][n] = (f32x4){0.f, 0.f, 0.f, 0.f};
        }

    if (isQ) {
        gemm_nb<1>(qbf, Wqb, Wqb, smem, rowA0, rowB0, lane, w, wm, wn, acc0,
                   acc1);
        const float scl = 0.125f * LOG2E;
#pragma unroll
        for (int m = 0; m < 4; ++m)
#pragma unroll
            for (int n = 0; n < 4; ++n)
#pragma unroll
                for (int r = 0; r < 4; ++r) {
                    int row = rowA0 + wm * 64 + m * 16 + g * 4 + r;
                    int col = rowB0 + wn * 64 + n * 16 + c;
                    int bb = row >> 10, nn = row & 1023, hh = col >> 6,
                        dd = col & 63;
                    Qb[((size_t)(bb * 12 + hh) << 16) + (nn << 6) + dd] =
                        f2bf(acc0[m][n][r] * scl);
                }
    } else {
        gemm_nb<2>(kvbf, Wkb, Wvb, smem, rowA0, rowB0, lane, w, wm, wn, acc0,
                   acc1);
#pragma unroll
        for (int m = 0; m < 4; ++m)
#pragma unroll
            for (int n = 0; n < 4; ++n)
#pragma unroll
                for (int r = 0; r < 4; ++r) {
                    int row = rowA0 + wm * 64 + m * 16 + g * 4 + r;
                    int col = rowB0 + wn * 64 + n * 16 + c;
                    int bb = row >> 10, nn = row & 1023, hh = col >> 6,
                        dd = col & 63;
                    Kb[((size_t)(bb * 12 + hh) << 16) + (nn << 6) + dd] =
                        f2bf(acc0[m][n][r]);
                    vlin[(size_t)row * 768 + col] = f2bf(acc1[m][n][r]);
                }
        __syncthreads();
        // transpose V tile (128 tokens x 128 douts) through LDS
#pragma unroll
        for (int m = 0; m < 4; ++m)
#pragma unroll
            for (int n = 0; n < 4; ++n)
#pragma unroll
                for (int r = 0; r < 4; ++r) {
                    int rl = wm * 64 + m * 16 + g * 4 + r;
                    int cl = wn * 64 + n * 16 + c;
                    smem[cl * 128 + rl] = f2bf(acc1[m][n][r]);
                }
        __syncthreads();
        int bb = rowA0 >> 10, nn0 = rowA0 & 1023;
        // write V^T with per-64-token k-permutation rho (PV fragment-ready)
#pragma unroll
        for (int j = 0; j < 8; ++j) {
            int idx = j * 256 + tid;
            int rT = idx >> 4, cc = idx & 15;
            int dout = rowB0 + rT, hh = dout >> 6, dd = dout & 63;
            const u16* srow = smem + rT * 128 + cc * 8;
            size_t robase = ((size_t)(bb * 12 + hh) * 64 + dd) * 1024;
#pragma unroll
            for (int e2 = 0; e2 < 4; ++e2) {
                int n0 = nn0 + cc * 8 + 2 * e2;
                int t6 = n0 & 63;
                int pos = (((t6 >> 1) & 1) << 5) | (((t6 >> 2) & 3) << 3) |
                          (((t6 >> 4) & 3) << 1) | (t6 & 1);
                u32 val = (u32)srow[2 * e2] | ((u32)srow[2 * e2 + 1] << 16);
                *(u32*)(VTg + robase + (n0 & ~63) + pos) = val;
            }
        }
    }
}

// ---------------------------------------------------------------- out GEMM (2-buffer, 2-barrier)
__global__ __launch_bounds__(256, 2) void k_gemm_out(
    const u16* __restrict__ xf, const u16* __restrict__ Wpb,
    const float* __restrict__ bp, float* __restrict__ out) {
    __shared__ __align__(16) u16 smem[24576];
    int bid = blockIdx.x;
    int logical = (bid & 7) * 48 + (bid >> 3);
    int c48 = logical % 48;
    int tm = (logical / 48) * 8 + c48 / 6, tn = c48 % 6;
    int tid = threadIdx.x, lane = tid & 63, w = tid >> 6;
    int g = lane >> 4, c = lane & 15;
    int wm = w >> 1, wn = w & 1;
    int rowA0 = tm * 128, rowB0 = tn * 128;

    f32x4 acc0[4][4], acc1[4][4];
#pragma unroll
    for (int m = 0; m < 4; ++m)
#pragma unroll
        for (int n = 0; n < 4; ++n) {
            acc0[m][n] = (f32x4){0.f, 0.f, 0.f, 0.f};
            acc1[m][n] = (f32x4){0.f, 0.f, 0.f, 0.f};
        }
    gemm_nb<1>(xf, Wpb, Wpb, smem, rowA0, rowB0, lane, w, wm, wn, acc0, acc1);

#pragma unroll
    for (int m = 0; m < 4; ++m)
#pragma unroll
        for (int n = 0; n < 4; ++n)
#pragma unroll
            for (int r = 0; r < 4; ++r) {
                int row = rowA0 + wm * 64 + m * 16 + g * 4 + r;
                int col = rowB0 + wn * 64 + n * 16 + c;
                out[(size_t)row * 768 + col] = acc0[m][n][r] + bp[col];
            }
}

// ---------------------------------------------------------------- attention (+fused combine, coalesced epilogue)
__global__ __launch_bounds__(256, 3) void k_attn(
    const u16* __restrict__ Qb, const u16* __restrict__ Kb,
    const u16* __restrict__ VTg, const u16* __restrict__ vlin,
    const float* __restrict__ glf, const float* __restrict__ ghf,
    const float* __restrict__ lfg, const float* __restrict__ hfg,
    u16* __restrict__ xfinal) {
    __shared__ __align__(16) u16 Ks[12288];  // 3 x 8KB
    __shared__ __align__(16) u16 Vs[12288];
    int b8 = blockIdx.x;
    int sw = (b8 & 7) * 96 + (b8 >> 3);  // XCD clustering: 12 heads per XCD
    int bh = sw >> 3, qblk = sw & 7;
    int bb = bh / 12, hh = bh % 12;
    int tid = threadIdx.x, lane = tid & 63, w = tid >> 6;
    int g = lane >> 4, c = lane & 15;
    const char* Kp = (const char*)(Kb + ((size_t)bh << 16));
    const char* Vp = (const char*)(VTg + ((size_t)bh << 16));
    const u16* Qp = Qb + ((size_t)bh << 16);
    int q0 = qblk * 128 + w * 32;

    short8 qf[2][2];
#pragma unroll
    for (int qb = 0; qb < 2; ++qb)
#pragma unroll
        for (int ks = 0; ks < 2; ++ks)
            qf[qb][ks] = *(const short8*)(Qp + (size_t)(q0 + qb * 16 + c) * 64 +
                                          ks * 32 + g * 8);

    f32x4 o[2][4];
#pragma unroll
    for (int qb = 0; qb < 2; ++qb)
#pragma unroll
        for (int n = 0; n < 4; ++n) o[qb][n] = (f32x4){0.f, 0.f, 0.f, 0.f};
    f32x4 o5[2];
    o5[0] = (f32x4){0.f, 0.f, 0.f, 0.f};
    o5[1] = (f32x4){0.f, 0.f, 0.f, 0.f};
    const short8 vones = (short8){(short)0x3F80, (short)0x3F80, (short)0x3F80,
                                  (short)0x3F80, (short)0x3F80, (short)0x3F80,
                                  (short)0x3F80, (short)0x3F80};

    int kgo[2], vgo[2], ldo[2];
#pragma unroll
    for (int h = 0; h < 2; ++h) {
        int idx = w * 64 + lane + h * 256;
        int row = idx >> 3;
        int colb = ((idx & 7) * 16) ^ ((row & 7) << 4);
        kgo[h] = row * 128 + colb;
        vgo[h] = row * 2048 + colb;
        ldo[h] = (w * 64 + h * 256) * 16;
    }

    auto stage = [&](int bi, int t) {
#pragma unroll
        for (int h = 0; h < 2; ++h) {
            g2l16(Kp + (size_t)t * 8192 + kgo[h], (char*)Ks + bi * 8192 + ldo[h]);
            g2l16(Vp + (size_t)t * 128 + vgo[h], (char*)Vs + bi * 8192 + ldo[h]);
        }
    };

    stage(0, 0);
    stage(1, 1);
    int cur = 0, nxt = 2;
    int cs = (c & 7) << 4;
    for (int t = 0; t < 16; ++t) {
        if (t < 15) asm volatile("s_waitcnt vmcnt(4)" ::: "memory");
        else        asm volatile("s_waitcnt vmcnt(0)" ::: "memory");
        __builtin_amdgcn_s_barrier();
        if (t < 14) stage(nxt, t + 2);
        const char* Kbase = (const char*)Ks + cur * 8192;
        const char* Vbase = (const char*)Vs + cur * 8192;
        short8 kf[4][2], vf[4][2];
#pragma unroll
        for (int m = 0; m < 4; ++m) {
            int rowb = (m * 16 + c) * 128;
#pragma unroll
            for (int ks = 0; ks < 2; ++ks)
                kf[m][ks] = *(const short8*)(Kbase + rowb +
                                             ((g * 16 + ks * 64) ^ cs));
        }
#pragma unroll
        for (int n = 0; n < 4; ++n) {
            int rowb = (n * 16 + c) * 128;
#pragma unroll
            for (int a = 0; a < 2; ++a)
                vf[n][a] = *(const short8*)(Vbase + rowb +
                                            ((a * 64 + g * 16) ^ cs));
        }
#pragma unroll
        for (int qb = 0; qb < 2; ++qb) {
            f32x4 s[4];
            __builtin_amdgcn_s_setprio(1);
#pragma unroll
            for (int m = 0; m < 4; ++m) {
                s[m] = __builtin_amdgcn_mfma_f32_16x16x32_bf16(
                    kf[m][0], qf[qb][0], (f32x4){0.f, 0.f, 0.f, 0.f}, 0, 0, 0);
                s[m] = __builtin_amdgcn_mfma_f32_16x16x32_bf16(
                    kf[m][1], qf[qb][1], s[m], 0, 0, 0);
            }
            __builtin_amdgcn_s_setprio(0);
            u32 P2[4][2];
#pragma unroll
            for (int m = 0; m < 4; ++m) {
#pragma unroll
                for (int r = 0; r < 4; ++r) s[m][r] = fexp2(s[m][r]);
                P2[m][0] = pk2(s[m][0], s[m][1]);
                P2[m][1] = pk2(s[m][2], s[m][3]);
            }
#pragma unroll
            for (int a = 0; a < 2; ++a) {
                union { u32 u[4]; short8 s8; } pu;
                pu.u[0] = P2[0][a]; pu.u[1] = P2[1][a];
                pu.u[2] = P2[2][a]; pu.u[3] = P2[3][a];
                __builtin_amdgcn_s_setprio(1);
#pragma unroll
                for (int n = 0; n < 4; ++n)
                    o[qb][n] = __builtin_amdgcn_mfma_f32_16x16x32_bf16(
                        pu.s8, vf[n][a], o[qb][n], 0, 0, 0);
                o5[qb] = __builtin_amdgcn_mfma_f32_16x16x32_bf16(
                    pu.s8, vones, o5[qb], 0, 0, 0);
                __builtin_amdgcn_s_setprio(0);
            }
        }
        cur = (cur == 2) ? 0 : cur + 1;
        nxt = (nxt == 2) ? 0 : nxt + 1;
    }
    __syncthreads();  // all waves done reading K/V before O-park reuses Ks

    // normalize and park bf16 O-tile in LDS (swizzled [128][64] u16)
    u16* X = &Ks[0];
#pragma unroll
    for (int qb = 0; qb < 2; ++qb) {
        float rl[4];
#pragma unroll
        for (int r = 0; r < 4; ++r) rl[r] = 1.0f / o5[qb][r];
#pragma unroll
        for (int n = 0; n < 4; ++n)
#pragma unroll
            for (int r = 0; r < 4; ++r) {
                int row = w * 32 + qb * 16 + 4 * g + r;
                int col = n * 16 + c;
                int byte = row * 128 + ((col * 2) ^ ((row & 3) << 4));
                *(u16*)((char*)X + byte) = f2bf(o[qb][n][r] * rl[r]);
            }
    }
    __syncthreads();
    // coalesced combine: thread -> (token, 32-d half)
    {
        int row = tid >> 1, half = tid & 1;
        size_t token = (size_t)bb * 1024 + qblk * 128 + row;
        float alf = glf[token * 12 + hh];
        float ahf = ghf[token * 12 + hh];
        int dbase = hh * 64 + half * 32;
        const u16* vbase = vlin + token * 768 + dbase;
        u16* obase = xfinal + token * 768 + dbase;
#pragma unroll
        for (int j = 0; j < 4; ++j) {
            int phys = ((half * 4 + j) ^ (row & 3)) * 16;
            short8 xa8 = *(const short8*)((char*)X + row * 128 + phys);
            short8 vl8 = *(const short8*)(vbase + j * 8);
            float4 lg0 = *(const float4*)(lfg + dbase + j * 8);
            float4 lg1 = *(const float4*)(lfg + dbase + j * 8 + 4);
            float4 hg0 = *(const float4*)(hfg + dbase + j * 8);
            float4 hg1 = *(const float4*)(hfg + dbase + j * 8 + 4);
            float lg[8] = {lg0.x, lg0.y, lg0.z, lg0.w, lg1.x, lg1.y, lg1.z, lg1.w};
            float hg[8] = {hg0.x, hg0.y, hg0.z, hg0.w, hg1.x, hg1.y, hg1.z, hg1.w};
            short8 oo;
#pragma unroll
            for (int e = 0; e < 8; ++e) {
                float xa = bf2f((u16)xa8[e]);
                float v = bf2f((u16)vl8[e]);
                float val = xa + xa * alf * lg[e] + ahf * (v - xa) * hg[e];
                oo[e] = f2bf(val);
            }
            *(short8*)(obase + j * 8) = oo;
        }
    }
}

// ---------------------------------------------------------------- launch
extern "C" void kernel_launch(void* const* d_in, const int* in_sizes, int n_in,
                              void* d_out, int out_size, void* d_ws,
                              size_t ws_size, hipStream_t stream) {
    const float* q_in = (const float*)d_in[0];
    const float* kv_in = (const float*)d_in[1];
    const float* Wq = (const float*)d_in[2];
    const float* Wk = (const float*)d_in[3];
    const float* Wv = (const float*)d_in[4];
    const float* Wp = (const float*)d_in[5];
    const float* bp = (const float*)d_in[6];
    const float* Wdy2 = (const float*)d_in[7];
    const float* bdy2 = (const float*)d_in[8];
    const float* Wdy = (const float*)d_in[9];
    const float* bdy = (const float*)d_in[10];
    const float* lfg = (const float*)d_in[11];
    const float* hfg = (const float*)d_in[12];
    const float* st_s = (const float*)d_in[13];
    const float* st_b = (const float*)d_in[14];
    float* out = (float*)d_out;

    char* ws = (char*)d_ws;
    const size_t MC2 = (size_t)8192 * 768 * 2;
    const size_t WB = (size_t)768 * 768 * 2;
    u16* qbf = (u16*)(ws);
    u16* kvbf = (u16*)(ws + MC2);
    u16* Wqb = (u16*)(ws + 2 * MC2);
    u16* Wkb = (u16*)(ws + 2 * MC2 + WB);
    u16* Wvb = (u16*)(ws + 2 * MC2 + 2 * WB);
    u16* Wpb = (u16*)(ws + 2 * MC2 + 3 * WB);
    u16* Qb = (u16*)(ws + 2 * MC2 + 4 * WB);
    u16* Kb = (u16*)(ws + 3 * MC2 + 4 * WB);
    u16* VTg = (u16*)(ws + 4 * MC2 + 4 * WB);
    u16* vlin = (u16*)(ws + 5 * MC2 + 4 * WB);
    float* glf = (float*)(ws + 6 * MC2 + 4 * WB);
    float* ghf = (float*)(ws + 6 * MC2 + 4 * WB + (size_t)8192 * 12 * 4);
    u16* wgb = (u16*)(ws + 6 * MC2 + 4 * WB + (size_t)8192 * 12 * 8);
    u16* xfinal = qbf;  // alias: qbf dead after qkv GEMM + gates

    k_cvt_all<<<7305, 256, 0, stream>>>(q_in, kv_in, Wq, Wk, Wv, Wp, Wdy2,
                                        Wdy, qbf, kvbf, Wqb, Wkb, Wvb, Wpb,
                                        wgb);
    k_gates<<<512, 64, 0, stream>>>(qbf, wgb, bdy2, bdy, st_s, st_b, glf, ghf);
    k_gemm_qkv<<<768, 256, 0, stream>>>(qbf, kvbf, Wqb, Wkb, Wvb, Qb, Kb,
                                        VTg, vlin);
    k_attn<<<768, 256, 0, stream>>>(Qb, Kb, VTg, vlin, glf, ghf, lfg, hfg,
                                    xfinal);
    k_gemm_out<<<384, 256, 0, stream>>>(xfinal, Wpb, bp, out);
}

// Round 9
// 133.746 us; speedup vs baseline: 1.0360x; 1.0360x over previous
//
#include <hip/hip_runtime.h>
#include <hip/hip_bf16.h>
#include <stdint.h>

typedef unsigned short u16;
typedef unsigned int u32;
typedef unsigned long long u64;
typedef __attribute__((ext_vector_type(8))) short short8;
typedef __attribute__((ext_vector_type(4))) float f32x4;

#define LOG2E 1.44269504f

static __device__ __forceinline__ u16 f2bf(float f) {
    u32 x = __float_as_uint(f);
    u32 r = (x + 0x7FFFu + ((x >> 16) & 1u)) >> 16;
    return (u16)r;
}
static __device__ __forceinline__ float bf2f(u16 u) {
    return __uint_as_float(((u32)u) << 16);
}
static __device__ __forceinline__ u32 pk2(float lo, float hi) {
    __hip_bfloat162 t = __float22bfloat162_rn(float2{lo, hi});
    union { __hip_bfloat162 b; u32 u; } cv;
    cv.b = t;
    return cv.u;
}
static __device__ __forceinline__ float fexp2(float x) {
#if __has_builtin(__builtin_amdgcn_exp2f)
    return __builtin_amdgcn_exp2f(x);
#else
    return exp2f(x);
#endif
}

static __device__ __forceinline__ void g2l16(const void* g, void* l) {
    __builtin_amdgcn_global_load_lds((const __attribute__((address_space(1))) void*)g,
                                     (__attribute__((address_space(3))) void*)l, 16, 0, 0);
}

// ---------------------------------------------------------------- convert (all tensors, one launch)
__global__ __launch_bounds__(256) void k_cvt_all(
    const float* __restrict__ q_in, const float* __restrict__ kv_in,
    const float* __restrict__ Wq, const float* __restrict__ Wk,
    const float* __restrict__ Wv, const float* __restrict__ Wp,
    const float* __restrict__ Wdy2, const float* __restrict__ Wdy,
    u16* __restrict__ qbf, u16* __restrict__ kvbf, u16* __restrict__ Wqb,
    u16* __restrict__ Wkb, u16* __restrict__ Wvb, u16* __restrict__ Wpb,
    u16* __restrict__ wgb) {
    int i = blockIdx.x * 256 + threadIdx.x;
    const float* src;
    u16* dst;
    int so, dofs;
    if (i < 786432) { src = q_in; dst = qbf; so = i; dofs = i; }
    else if (i < 1572864) { src = kv_in; dst = kvbf; so = i - 786432; dofs = so; }
    else if (i < 1646592) { src = Wq; dst = Wqb; so = i - 1572864; dofs = so; }
    else if (i < 1720320) { src = Wk; dst = Wkb; so = i - 1646592; dofs = so; }
    else if (i < 1794048) { src = Wv; dst = Wvb; so = i - 1720320; dofs = so; }
    else if (i < 1867776) { src = Wp; dst = Wpb; so = i - 1794048; dofs = so; }
    else if (i < 1870080) {
        int e = i - 1867776;
        dst = wgb; dofs = e;
        if (e < 1152) { src = Wdy2; so = e; }
        else { src = Wdy; so = e - 1152; }
    } else return;
    const float4* p = (const float4*)src + (size_t)so * 2;
    float4 a = p[0], b = p[1];
    short8 o;
    o[0] = f2bf(a.x); o[1] = f2bf(a.y); o[2] = f2bf(a.z); o[3] = f2bf(a.w);
    o[4] = f2bf(b.x); o[5] = f2bf(b.y); o[6] = f2bf(b.z); o[7] = f2bf(b.w);
    *((short8*)dst + dofs) = o;
}

// ---------------------------------------------------------------- gates (1-wave blocks)
__global__ __launch_bounds__(64) void k_gates(
    const u16* __restrict__ qbf, const u16* __restrict__ wgb,
    const float* __restrict__ bdy2, const float* __restrict__ bdy,
    const float* __restrict__ star_s, const float* __restrict__ star_b,
    float* __restrict__ glf, float* __restrict__ ghf) {
    int lane = threadIdx.x;
    int g = lane >> 4, c = lane & 15;
    int row0 = blockIdx.x * 16;
    float ss = star_s[0], sb = star_b[0];
    f32x4 acc[2];
    acc[0] = (f32x4){0.f, 0.f, 0.f, 0.f};
    acc[1] = (f32x4){0.f, 0.f, 0.f, 0.f};
    for (int t = 0; t < 24; ++t) {
        int k0 = t * 32;
        short8 x8 = *(const short8*)(qbf + (size_t)(row0 + c) * 768 + k0 + g * 8);
        float f[8];
#pragma unroll
        for (int j = 0; j < 8; ++j) {
            float x = fmaxf(bf2f((u16)x8[j]), 0.f);
            f[j] = ss * x * x + sb;
        }
        union { u32 u[4]; short8 s8; } au;
#pragma unroll
        for (int j = 0; j < 4; ++j) au.u[j] = pk2(f[2 * j], f[2 * j + 1]);
        short8 b0 = *(const short8*)(wgb + (size_t)c * 768 + k0 + g * 8);
        short8 b1 = (short8){0, 0, 0, 0, 0, 0, 0, 0};
        if (c < 8)
            b1 = *(const short8*)(wgb + (size_t)(16 + c) * 768 + k0 + g * 8);
        acc[0] = __builtin_amdgcn_mfma_f32_16x16x32_bf16(au.s8, b0, acc[0], 0, 0, 0);
        acc[1] = __builtin_amdgcn_mfma_f32_16x16x32_bf16(au.s8, b1, acc[1], 0, 0, 0);
    }
#pragma unroll
    for (int n = 0; n < 2; ++n)
#pragma unroll
        for (int r = 0; r < 4; ++r) {
            int token = row0 + g * 4 + r;
            int o = n * 16 + c;
            float v = acc[n][r];
            if (o < 12) {
                glf[(size_t)token * 12 + o] = tanhf(v + bdy2[o]);
            } else if (o < 24) {
                float x = v + bdy[o - 12];
                float sp = (x > 15.f) ? x : log1pf(expf(x));
                float d2 = sp * sp;
                ghf[(size_t)token * 12 + (o - 12)] = 2.f * d2 / (d2 + 0.3678f);
            }
        }
}

// ---------------------------------------------------------------- GEMM core
// pair-line swizzled LDS (zero-conflict) + 3-buffer counted-vmcnt pipeline
__device__ __forceinline__ void gemm_core(const u16* __restrict__ A,
                                          const u16* __restrict__ W, u16* As,
                                          u16* Bs, int rowA0, int rowB0,
                                          int lane, int w, int wm, int wn,
                                          f32x4 acc[4][4]) {
    int g = lane >> 4, c = lane & 15;
#pragma unroll
    for (int m = 0; m < 4; ++m)
#pragma unroll
        for (int n = 0; n < 4; ++n) acc[m][n] = (f32x4){0.f, 0.f, 0.f, 0.f};

    auto stage = [&](int buf, int k0) {
#pragma unroll
        for (int j = 0; j < 2; ++j) {
            int L = w * 128 + j * 64 + lane;  // 16B unit 0..511
            int p = L >> 3, s8 = L & 7;
            int t2 = s8 ^ (p & 7);
            int row = 2 * p + (t2 >> 2);
            int chunk = t2 & 3;
            size_t go = (size_t)row * 768 + k0 + chunk * 8;
            g2l16(A + (size_t)rowA0 * 768 + go, As + buf * 4096 + L * 8);
            g2l16(W + (size_t)rowB0 * 768 + go, Bs + buf * 4096 + L * 8);
        }
    };

    stage(0, 0);
    stage(1, 32);
    int cur = 0, nxt = 2;
    for (int t = 0; t < 24; ++t) {
        if (t < 23) asm volatile("s_waitcnt vmcnt(4)" ::: "memory");
        else        asm volatile("s_waitcnt vmcnt(0)" ::: "memory");
        __builtin_amdgcn_s_barrier();
        if (t < 22) stage(nxt, (t + 2) * 32);
        short8 a[4], b[4];
#pragma unroll
        for (int m = 0; m < 4; ++m) {
            int row = wm * 64 + m * 16 + c;
            int off = (row >> 1) * 64 +
                      ((((row & 1) << 2) | g) ^ ((row >> 1) & 7)) * 8;
            a[m] = *(const short8*)(As + cur * 4096 + off);
        }
#pragma unroll
        for (int n = 0; n < 4; ++n) {
            int row = wn * 64 + n * 16 + c;
            int off = (row >> 1) * 64 +
                      ((((row & 1) << 2) | g) ^ ((row >> 1) & 7)) * 8;
            b[n] = *(const short8*)(Bs + cur * 4096 + off);
        }
        __builtin_amdgcn_s_setprio(1);
#pragma unroll
        for (int m = 0; m < 4; ++m)
#pragma unroll
            for (int n = 0; n < 4; ++n)
                acc[m][n] = __builtin_amdgcn_mfma_f32_16x16x32_bf16(
                    a[m], b[n], acc[m][n], 0, 0, 0);
        __builtin_amdgcn_s_setprio(0);
        cur = (cur == 2) ? 0 : cur + 1;
        nxt = (nxt == 2) ? 0 : nxt + 1;
    }
}

// bf16 tile park: [row 0..127][col 0..127] u16, row stride 256B,
// byte = row*256 + ((col*2) ^ (((row>>2)&3)<<5))  -> conflict-free both ways
static __device__ __forceinline__ int park_wb(int row, int col) {
    return row * 256 + ((col * 2) ^ (((row >> 2) & 3) << 5));
}
static __device__ __forceinline__ int park_rb(int srow, int sch) {
    return srow * 256 + ((sch * 16) ^ (((srow >> 2) & 3) << 5));
}

// ---------------------------------------------------------------- QKV GEMM (uniform blocks)
__global__ __launch_bounds__(256, 3) void k_gemm_qkv(
    const u16* __restrict__ qbf, const u16* __restrict__ kvbf,
    const u16* __restrict__ Wqb, const u16* __restrict__ Wkb,
    const u16* __restrict__ Wvb, u16* __restrict__ Qb, u16* __restrict__ Kb,
    u16* __restrict__ VTg, u16* __restrict__ vlin) {
    __shared__ __align__(16) u16 smem[24576];  // 48 KB: 3-buf A + 3-buf B
    u16* As = smem;
    u16* Bs = smem + 12288;
    int bid = blockIdx.x;
    int logical = (bid & 7) * 144 + (bid >> 3);
    int panel = logical / 18, sub = logical % 18;
    int type = sub / 6, tn = sub % 6;
    int tid = threadIdx.x, lane = tid & 63, w = tid >> 6;
    int g = lane >> 4, c = lane & 15;
    int wm = w >> 1, wn = w & 1;
    int rowA0 = panel * 128, rowB0 = tn * 128;
    const u16* A = (type == 0) ? qbf : kvbf;
    const u16* W = (type == 0) ? Wqb : (type == 1) ? Wkb : Wvb;

    f32x4 acc[4][4];
    gemm_core(A, W, As, Bs, rowA0, rowB0, lane, w, wm, wn, acc);
    __syncthreads();  // all waves done with staged LDS before re-park

    if (type < 2) {
        u16* dst = (type == 0) ? Qb : Kb;
        const float scl = (type == 0) ? (0.125f * LOG2E) : 1.0f;
#pragma unroll
        for (int m = 0; m < 4; ++m)
#pragma unroll
            for (int n = 0; n < 4; ++n)
#pragma unroll
                for (int r = 0; r < 4; ++r) {
                    int row = wm * 64 + m * 16 + g * 4 + r;
                    int col = wn * 64 + n * 16 + c;
                    *(u16*)((char*)smem + park_wb(row, col)) =
                        f2bf(acc[m][n][r] * scl);
                }
        __syncthreads();
#pragma unroll
        for (int j = 0; j < 8; ++j) {
            int idx = j * 256 + tid;
            int srow = idx >> 4, sch = idx & 15;
            short8 v = *(const short8*)((char*)smem + park_rb(srow, sch));
            int token = rowA0 + srow;
            int col0 = rowB0 + sch * 8;
            int bb = token >> 10, nn = token & 1023, hh = col0 >> 6,
                dd = col0 & 63;
            *(short8*)(dst + ((size_t)(bb * 12 + hh) << 16) + (nn << 6) + dd) = v;
        }
    } else {
        // V: park row-major -> coalesced vlin store
#pragma unroll
        for (int m = 0; m < 4; ++m)
#pragma unroll
            for (int n = 0; n < 4; ++n)
#pragma unroll
                for (int r = 0; r < 4; ++r) {
                    int row = wm * 64 + m * 16 + g * 4 + r;
                    int col = wn * 64 + n * 16 + c;
                    *(u16*)((char*)smem + park_wb(row, col)) = f2bf(acc[m][n][r]);
                }
        __syncthreads();
#pragma unroll
        for (int j = 0; j < 8; ++j) {
            int idx = j * 256 + tid;
            int srow = idx >> 4, sch = idx & 15;
            short8 v = *(const short8*)((char*)smem + park_rb(srow, sch));
            *(short8*)(vlin + (size_t)(rowA0 + srow) * 768 + rowB0 + sch * 8) = v;
        }
        __syncthreads();
        // transpose park (128 cols x 128 tokens) for V^T
#pragma unroll
        for (int m = 0; m < 4; ++m)
#pragma unroll
            for (int n = 0; n < 4; ++n)
#pragma unroll
                for (int r = 0; r < 4; ++r) {
                    int rl = wm * 64 + m * 16 + g * 4 + r;
                    int cl = wn * 64 + n * 16 + c;
                    smem[cl * 128 + rl] = f2bf(acc[m][n][r]);
                }
        __syncthreads();
        int bb = rowA0 >> 10, nn0 = rowA0 & 1023;
        // write V^T with per-64-token k-permutation rho (PV fragment-ready)
#pragma unroll
        for (int j = 0; j < 8; ++j) {
            int idx = j * 256 + tid;
            int rT = idx >> 4, cc = idx & 15;
            int dout = rowB0 + rT, hh = dout >> 6, dd = dout & 63;
            const u16* srow = smem + rT * 128 + cc * 8;
            size_t robase = ((size_t)(bb * 12 + hh) * 64 + dd) * 1024;
#pragma unroll
            for (int e2 = 0; e2 < 4; ++e2) {
                int n0 = nn0 + cc * 8 + 2 * e2;
                int t6 = n0 & 63;
                int pos = (((t6 >> 1) & 1) << 5) | (((t6 >> 2) & 3) << 3) |
                          (((t6 >> 4) & 3) << 1) | (t6 & 1);
                u32 val = (u32)srow[2 * e2] | ((u32)srow[2 * e2 + 1] << 16);
                *(u32*)(VTg + robase + (n0 & ~63) + pos) = val;
            }
        }
    }
}

// ---------------------------------------------------------------- out GEMM (f32 park, 2-pass)
__global__ __launch_bounds__(256, 3) void k_gemm_out(
    const u16* __restrict__ xf, const u16* __restrict__ Wpb,
    const float* __restrict__ bp, float* __restrict__ out) {
    __shared__ __align__(16) u16 smem[24576];
    u16* As = smem;
    u16* Bs = smem + 12288;
    int bid = blockIdx.x;
    int logical = (bid & 7) * 48 + (bid >> 3);
    int c48 = logical % 48;
    int tm = (logical / 48) * 8 + c48 / 6, tn = c48 % 6;
    int tid = threadIdx.x, lane = tid & 63, w = tid >> 6;
    int g = lane >> 4, c = lane & 15;
    int wm = w >> 1, wn = w & 1;
    int rowA0 = tm * 128, rowB0 = tn * 128;

    f32x4 acc[4][4];
    gemm_core(xf, Wpb, As, Bs, rowA0, rowB0, lane, w, wm, wn, acc);

    float bias[4];
#pragma unroll
    for (int n = 0; n < 4; ++n) bias[n] = bp[rowB0 + wn * 64 + n * 16 + c];

    char* F = (char*)smem;  // [64 rows][128 cols] f32, row stride 512B
#pragma unroll
    for (int p = 0; p < 2; ++p) {
        __syncthreads();
        if (wm == p) {
#pragma unroll
            for (int m = 0; m < 4; ++m)
#pragma unroll
                for (int n = 0; n < 4; ++n)
#pragma unroll
                    for (int r = 0; r < 4; ++r) {
                        int lrow = m * 16 + g * 4 + r;
                        int col = wn * 64 + n * 16 + c;
                        int byte = lrow * 512 +
                                   ((col * 4) ^ (((lrow >> 2) & 3) << 6));
                        *(float*)(F + byte) = acc[m][n][r] + bias[n];
                    }
        }
        __syncthreads();
#pragma unroll
        for (int j = 0; j < 8; ++j) {
            int idx = j * 256 + tid;
            int srow = idx >> 5, sch = idx & 31;
            int byte = srow * 512 + ((sch * 16) ^ (((srow >> 2) & 3) << 6));
            float4 v = *(const float4*)(F + byte);
            *(float4*)(out + (size_t)(rowA0 + p * 64 + srow) * 768 + rowB0 +
                       sch * 4) = v;
        }
    }
}

// ---------------------------------------------------------------- attention (+fused combine, coalesced epilogue)
__global__ __launch_bounds__(256, 3) void k_attn(
    const u16* __restrict__ Qb, const u16* __restrict__ Kb,
    const u16* __restrict__ VTg, const u16* __restrict__ vlin,
    const float* __restrict__ glf, const float* __restrict__ ghf,
    const float* __restrict__ lfg, const float* __restrict__ hfg,
    u16* __restrict__ xfinal) {
    __shared__ __align__(16) u16 Ks[12288];  // 3 x 8KB
    __shared__ __align__(16) u16 Vs[12288];
    int b8 = blockIdx.x;
    int sw = (b8 & 7) * 96 + (b8 >> 3);  // XCD clustering: 12 heads per XCD
    int bh = sw >> 3, qblk = sw & 7;
    int bb = bh / 12, hh = bh % 12;
    int tid = threadIdx.x, lane = tid & 63, w = tid >> 6;
    int g = lane >> 4, c = lane & 15;
    const char* Kp = (const char*)(Kb + ((size_t)bh << 16));
    const char* Vp = (const char*)(VTg + ((size_t)bh << 16));
    const u16* Qp = Qb + ((size_t)bh << 16);
    int q0 = qblk * 128 + w * 32;

    short8 qf[2][2];
#pragma unroll
    for (int qb = 0; qb < 2; ++qb)
#pragma unroll
        for (int ks = 0; ks < 2; ++ks)
            qf[qb][ks] = *(const short8*)(Qp + (size_t)(q0 + qb * 16 + c) * 64 +
                                          ks * 32 + g * 8);

    f32x4 o[2][4];
#pragma unroll
    for (int qb = 0; qb < 2; ++qb)
#pragma unroll
        for (int n = 0; n < 4; ++n) o[qb][n] = (f32x4){0.f, 0.f, 0.f, 0.f};
    f32x4 o5[2];
    o5[0] = (f32x4){0.f, 0.f, 0.f, 0.f};
    o5[1] = (f32x4){0.f, 0.f, 0.f, 0.f};
    const short8 vones = (short8){(short)0x3F80, (short)0x3F80, (short)0x3F80,
                                  (short)0x3F80, (short)0x3F80, (short)0x3F80,
                                  (short)0x3F80, (short)0x3F80};

    int kgo[2], vgo[2], ldo[2];
#pragma unroll
    for (int h = 0; h < 2; ++h) {
        int idx = w * 64 + lane + h * 256;
        int row = idx >> 3;
        int colb = ((idx & 7) * 16) ^ ((row & 7) << 4);
        kgo[h] = row * 128 + colb;
        vgo[h] = row * 2048 + colb;
        ldo[h] = (w * 64 + h * 256) * 16;
    }

    auto stage = [&](int bi, int t) {
#pragma unroll
        for (int h = 0; h < 2; ++h) {
            g2l16(Kp + (size_t)t * 8192 + kgo[h], (char*)Ks + bi * 8192 + ldo[h]);
            g2l16(Vp + (size_t)t * 128 + vgo[h], (char*)Vs + bi * 8192 + ldo[h]);
        }
    };

    stage(0, 0);
    stage(1, 1);
    int cur = 0, nxt = 2;
    int cs = (c & 7) << 4;
    for (int t = 0; t < 16; ++t) {
        if (t < 15) asm volatile("s_waitcnt vmcnt(4)" ::: "memory");
        else        asm volatile("s_waitcnt vmcnt(0)" ::: "memory");
        __builtin_amdgcn_s_barrier();
        if (t < 14) stage(nxt, t + 2);
        const char* Kbase = (const char*)Ks + cur * 8192;
        const char* Vbase = (const char*)Vs + cur * 8192;
        short8 kf[4][2], vf[4][2];
#pragma unroll
        for (int m = 0; m < 4; ++m) {
            int rowb = (m * 16 + c) * 128;
#pragma unroll
            for (int ks = 0; ks < 2; ++ks)
                kf[m][ks] = *(const short8*)(Kbase + rowb +
                                             ((g * 16 + ks * 64) ^ cs));
        }
#pragma unroll
        for (int n = 0; n < 4; ++n) {
            int rowb = (n * 16 + c) * 128;
#pragma unroll
            for (int a = 0; a < 2; ++a)
                vf[n][a] = *(const short8*)(Vbase + rowb +
                                            ((a * 64 + g * 16) ^ cs));
        }
#pragma unroll
        for (int qb = 0; qb < 2; ++qb) {
            f32x4 s[4];
            __builtin_amdgcn_s_setprio(1);
#pragma unroll
            for (int m = 0; m < 4; ++m) {
                s[m] = __builtin_amdgcn_mfma_f32_16x16x32_bf16(
                    kf[m][0], qf[qb][0], (f32x4){0.f, 0.f, 0.f, 0.f}, 0, 0, 0);
                s[m] = __builtin_amdgcn_mfma_f32_16x16x32_bf16(
                    kf[m][1], qf[qb][1], s[m], 0, 0, 0);
            }
            __builtin_amdgcn_s_setprio(0);
            u32 P2[4][2];
#pragma unroll
            for (int m = 0; m < 4; ++m) {
#pragma unroll
                for (int r = 0; r < 4; ++r) s[m][r] = fexp2(s[m][r]);
                P2[m][0] = pk2(s[m][0], s[m][1]);
                P2[m][1] = pk2(s[m][2], s[m][3]);
            }
#pragma unroll
            for (int a = 0; a < 2; ++a) {
                union { u32 u[4]; short8 s8; } pu;
                pu.u[0] = P2[0][a]; pu.u[1] = P2[1][a];
                pu.u[2] = P2[2][a]; pu.u[3] = P2[3][a];
                __builtin_amdgcn_s_setprio(1);
#pragma unroll
                for (int n = 0; n < 4; ++n)
                    o[qb][n] = __builtin_amdgcn_mfma_f32_16x16x32_bf16(
                        pu.s8, vf[n][a], o[qb][n], 0, 0, 0);
                o5[qb] = __builtin_amdgcn_mfma_f32_16x16x32_bf16(
                    pu.s8, vones, o5[qb], 0, 0, 0);
                __builtin_amdgcn_s_setprio(0);
            }
        }
        cur = (cur == 2) ? 0 : cur + 1;
        nxt = (nxt == 2) ? 0 : nxt + 1;
    }
    __syncthreads();  // all waves done reading K/V before O-park reuses Ks

    // normalize and park bf16 O-tile in LDS (swizzled [128][64] u16)
    u16* X = &Ks[0];
#pragma unroll
    for (int qb = 0; qb < 2; ++qb) {
        float rl[4];
#pragma unroll
        for (int r = 0; r < 4; ++r) rl[r] = 1.0f / o5[qb][r];
#pragma unroll
        for (int n = 0; n < 4; ++n)
#pragma unroll
            for (int r = 0; r < 4; ++r) {
                int row = w * 32 + qb * 16 + 4 * g + r;
                int col = n * 16 + c;
                int byte = row * 128 + ((col * 2) ^ ((row & 3) << 4));
                *(u16*)((char*)X + byte) = f2bf(o[qb][n][r] * rl[r]);
            }
    }
    __syncthreads();
    // coalesced combine: thread -> (token, 32-d half)
    {
        int row = tid >> 1, half = tid & 1;
        size_t token = (size_t)bb * 1024 + qblk * 128 + row;
        float alf = glf[token * 12 + hh];
        float ahf = ghf[token * 12 + hh];
        int dbase = hh * 64 + half * 32;
        const u16* vbase = vlin + token * 768 + dbase;
        u16* obase = xfinal + token * 768 + dbase;
#pragma unroll
        for (int j = 0; j < 4; ++j) {
            int phys = ((half * 4 + j) ^ (row & 3)) * 16;
            short8 xa8 = *(const short8*)((char*)X + row * 128 + phys);
            short8 vl8 = *(const short8*)(vbase + j * 8);
            float4 lg0 = *(const float4*)(lfg + dbase + j * 8);
            float4 lg1 = *(const float4*)(lfg + dbase + j * 8 + 4);
            float4 hg0 = *(const float4*)(hfg + dbase + j * 8);
            float4 hg1 = *(const float4*)(hfg + dbase + j * 8 + 4);
            float lg[8] = {lg0.x, lg0.y, lg0.z, lg0.w, lg1.x, lg1.y, lg1.z, lg1.w};
            float hg[8] = {hg0.x, hg0.y, hg0.z, hg0.w, hg1.x, hg1.y, hg1.z, hg1.w};
            short8 oo;
#pragma unroll
            for (int e = 0; e < 8; ++e) {
                float xa = bf2f((u16)xa8[e]);
                float v = bf2f((u16)vl8[e]);
                float val = xa + xa * alf * lg[e] + ahf * (v - xa) * hg[e];
                oo[e] = f2bf(val);
            }
            *(short8*)(obase + j * 8) = oo;
        }
    }
}

// ---------------------------------------------------------------- launch
extern "C" void kernel_launch(void* const* d_in, const int* in_sizes, int n_in,
                              void* d_out, int out_size, void* d_ws,
                              size_t ws_size, hipStream_t stream) {
    const float* q_in = (const float*)d_in[0];
    const float* kv_in = (const float*)d_in[1];
    const float* Wq = (const float*)d_in[2];
    const float* Wk = (const float*)d_in[3];
    const float* Wv = (const float*)d_in[4];
    const float* Wp = (const float*)d_in[5];
    const float* bp = (const float*)d_in[6];
    const float* Wdy2 = (const float*)d_in[7];
    const float* bdy2 = (const float*)d_in[8];
    const float* Wdy = (const float*)d_in[9];
    const float* bdy = (const float*)d_in[10];
    const float* lfg = (const float*)d_in[11];
    const float* hfg = (const float*)d_in[12];
    const float* st_s = (const float*)d_in[13];
    const float* st_b = (const float*)d_in[14];
    float* out = (float*)d_out;

    char* ws = (char*)d_ws;
    const size_t MC2 = (size_t)8192 * 768 * 2;
    const size_t WB = (size_t)768 * 768 * 2;
    u16* qbf = (u16*)(ws);
    u16* kvbf = (u16*)(ws + MC2);
    u16* Wqb = (u16*)(ws + 2 * MC2);
    u16* Wkb = (u16*)(ws + 2 * MC2 + WB);
    u16* Wvb = (u16*)(ws + 2 * MC2 + 2 * WB);
    u16* Wpb = (u16*)(ws + 2 * MC2 + 3 * WB);
    u16* Qb = (u16*)(ws + 2 * MC2 + 4 * WB);
    u16* Kb = (u16*)(ws + 3 * MC2 + 4 * WB);
    u16* VTg = (u16*)(ws + 4 * MC2 + 4 * WB);
    u16* vlin = (u16*)(ws + 5 * MC2 + 4 * WB);
    float* glf = (float*)(ws + 6 * MC2 + 4 * WB);
    float* ghf = (float*)(ws + 6 * MC2 + 4 * WB + (size_t)8192 * 12 * 4);
    u16* wgb = (u16*)(ws + 6 * MC2 + 4 * WB + (size_t)8192 * 12 * 8);
    u16* xfinal = qbf;  // alias: qbf dead after qkv GEMM + gates

    k_cvt_all<<<7305, 256, 0, stream>>>(q_in, kv_in, Wq, Wk, Wv, Wp, Wdy2,
                                        Wdy, qbf, kvbf, Wqb, Wkb, Wvb, Wpb,
                                        wgb);
    k_gates<<<512, 64, 0, stream>>>(qbf, wgb, bdy2, bdy, st_s, st_b, glf, ghf);
    k_gemm_qkv<<<1152, 256, 0, stream>>>(qbf, kvbf, Wqb, Wkb, Wvb, Qb, Kb,
                                         VTg, vlin);
    k_attn<<<768, 256, 0, stream>>>(Qb, Kb, VTg, vlin, glf, ghf, lfg, hfg,
                                    xfinal);
    k_gemm_out<<<384, 256, 0, stream>>>(xfinal, Wpb, bp, out);
}